// Round 4
// baseline (335.490 us; speedup 1.0000x reference)
//
#include <hip/hip_runtime.h>

#define NB  64
#define ND  128
#define NLC 1024
#define NLQ 256
#define FNEG (-1e30f)

typedef __bf16 bf16x8 __attribute__((ext_vector_type(8)));
typedef float f32x4 __attribute__((ext_vector_type(4)));

__device__ __forceinline__ ushort f2bf(float x) {
  unsigned u = __float_as_uint(x);
  return (ushort)((u + 0x7fffu + ((u >> 16) & 1u)) >> 16);
}
__device__ __forceinline__ bf16x8 ldfrag(const ushort* p) {
  return *reinterpret_cast<const bf16x8*>(p);
}
__device__ __forceinline__ uint4 pack8(float a0, float a1, float a2, float a3,
                                       float a4, float a5, float a6, float a7) {
  uint4 pk;
  pk.x = (unsigned)f2bf(a0) | ((unsigned)f2bf(a1) << 16);
  pk.y = (unsigned)f2bf(a2) | ((unsigned)f2bf(a3) << 16);
  pk.z = (unsigned)f2bf(a4) | ((unsigned)f2bf(a5) << 16);
  pk.w = (unsigned)f2bf(a6) | ((unsigned)f2bf(a7) << 16);
  return pk;
}

// -------------------------------------------------------------------------
// Fused convert+bias. Reads C,Q once. Produces:
//  Ctw3[b][l][d]=bf16(C*w3), Cn16[b][d][l]=bf16(C), c1[b][l]=C.w1
//  Qt16[b][m][d]=bf16(Q),    Qn16[b][d][m]=bf16(Q), q2[b][m]=Q.w2
__global__ __launch_bounds__(256) void convert_bias(
    const float* __restrict__ C, const float* __restrict__ Q,
    const float* __restrict__ w,
    ushort* __restrict__ Ctw3, ushort* __restrict__ Qt16,
    ushort* __restrict__ Cn16, ushort* __restrict__ Qn16,
    float* __restrict__ c1, float* __restrict__ q2) {
  __shared__ float tile[128][65];
  __shared__ float w12s[128];
  __shared__ float w3s[128];
  int b = blockIdx.y, s = blockIdx.x;
  int t = threadIdx.x;
  bool isC = (s < 16);
  int stride = isC ? NLC : NLQ;
  int x0 = isC ? s * 64 : (s - 16) * 64;
  const float* src = isC ? (C + (size_t)b * ND * NLC) : (Q + (size_t)b * ND * NLQ);
  ushort* packDst = isC ? (Cn16 + (size_t)b * ND * NLC) : (Qn16 + (size_t)b * ND * NLQ);
  ushort* trDst   = isC ? (Ctw3 + (size_t)b * NLC * ND) : (Qt16 + (size_t)b * NLQ * ND);
  float* biasDst  = isC ? (c1 + b * NLC) : (q2 + b * NLQ);

  if (t < 128) {
    w12s[t] = isC ? w[t] : w[ND + t];
    w3s[t] = isC ? w[2 * ND + t] : 1.0f;
  }

  // load + straight bf16 pack (32 elems/thread)
#pragma unroll
  for (int it = 0; it < 4; ++it) {
    int e = (it * 256 + t) * 8;
    int d = e >> 6, c = e & 63;
    const float* sp = src + (size_t)d * stride + x0 + c;
    float4 v0 = *(const float4*)sp, v1 = *(const float4*)(sp + 4);
    *(uint4*)(packDst + (size_t)d * stride + x0 + c) =
        pack8(v0.x, v0.y, v0.z, v0.w, v1.x, v1.y, v1.z, v1.w);
    *(float4*)(&tile[d][c]) = v0;
    *(float4*)(&tile[d][c + 4]) = v1;
  }
  __syncthreads();

  // bias: l = t>>2, quarter g = t&3 sums 32 d's (rotated order: 2-way banks)
  {
    int l = t >> 2, g = t & 3;
    float p = 0.f;
#pragma unroll
    for (int k = 0; k < 32; ++k) {
      int kp = (k + 8 * g) & 31;
      int d = g * 32 + kp;
      p += tile[d][l] * w12s[d];
    }
    p += __shfl_xor(p, 1);
    p += __shfl_xor(p, 2);
    if (g == 0) biasDst[x0 + l] = p;
  }

  // transpose store: thread (l = t>>2, q = t&3) covers d in [q*32, q*32+32)
  {
    int l = t >> 2, q = t & 3;
    float vals[32];
#pragma unroll
    for (int k = 0; k < 32; ++k) {
      int kp = (k + 8 * q) & 31;
      int d = q * 32 + kp;
      vals[kp] = tile[d][l] * w3s[d];
    }
    ushort* row = trDst + (size_t)(x0 + l) * ND + q * 32;
#pragma unroll
    for (int k8 = 0; k8 < 4; ++k8) {
      *(uint4*)(row + k8 * 8) = pack8(
          vals[k8 * 8 + 0], vals[k8 * 8 + 1], vals[k8 * 8 + 2], vals[k8 * 8 + 3],
          vals[k8 * 8 + 4], vals[k8 * 8 + 5], vals[k8 * 8 + 6], vals[k8 * 8 + 7]);
    }
  }
}

// -------------------------------------------------------------------------
// Fused: S-tile (128 l x 256 m) MFMA + biases; row max/sum; e1[l][m]=bf16
// exp(S+qneg-rmax); h[m][l]=bf16(e1*exp(rmax+cneg-chunkmax)); column partial
// sums of e1*rowfac.
__global__ __launch_bounds__(512) void score_stats(
    const ushort* __restrict__ Ctw3, const ushort* __restrict__ Qt16,
    const float* __restrict__ c1, const float* __restrict__ q2,
    const float* __restrict__ cmask, const float* __restrict__ qmask,
    ushort* __restrict__ e1g, ushort* __restrict__ hg,
    float* __restrict__ rscale_g, float* __restrict__ psum_part,
    float* __restrict__ chunkmax_g) {
  __shared__ union {
    struct { __align__(16) ushort As[128 * 32]; __align__(16) ushort Bs[256 * 32]; } s;
    __align__(16) ushort bounce[128 * 264];   // e1 [l][m] pad 264
    __align__(16) ushort hb[256 * 132];       // h  [m][l] pad 132
  } u;
  __shared__ float rowred[128][4];
  __shared__ float rowsum[128][4];
  __shared__ float colred[256][2];
  __shared__ float rmaxs[128];
  __shared__ float rcs[128];
  __shared__ float cnegs[128];
  __shared__ float qnegs[256];
  __shared__ float c1s[128];
  __shared__ float q2s[256];
  __shared__ float chunkmax_s;

  int b = blockIdx.y, chunk = blockIdx.x, l0 = chunk * 128;
  int t = threadIdx.x, lane = t & 63, wid = t >> 6;
  int wy = wid >> 2, wx = wid & 3, ln = lane & 15, qd = lane >> 4;

  if (t < 128) {
    c1s[t] = c1[b * NLC + l0 + t];
    cnegs[t] = (1.f - cmask[b * NLC + l0 + t]) * FNEG;
  } else if (t < 384) {
    int m = t - 128;
    q2s[m] = q2[b * NLQ + m];
    qnegs[m] = (1.f - qmask[b * NLQ + m]) * FNEG;
  }

  const ushort* Ab = Ctw3 + (size_t)b * NLC * ND;
  const ushort* Bb = Qt16 + (size_t)b * NLQ * ND;
  f32x4 acc[4][4];
#pragma unroll
  for (int i = 0; i < 4; ++i)
#pragma unroll
    for (int j = 0; j < 4; ++j) acc[i][j] = (f32x4){0.f, 0.f, 0.f, 0.f};

  for (int kk = 0; kk < ND; kk += 32) {
#pragma unroll
    for (int p = 0; p < 3; ++p) {
      int e4 = p * 512 + t;
      if (e4 < 512) {
        int r = e4 >> 2, cc = (e4 & 3) * 8;
        *(int4*)(u.s.As + r * 32 + cc) = *(const int4*)(Ab + (size_t)(l0 + r) * ND + kk + cc);
      } else {
        int e = e4 - 512;
        int r = e >> 2, cc = (e & 3) * 8;
        *(int4*)(u.s.Bs + r * 32 + cc) = *(const int4*)(Bb + (size_t)r * ND + kk + cc);
      }
    }
    __syncthreads();
    bf16x8 af[4], bfr[4];
#pragma unroll
    for (int i = 0; i < 4; ++i) {
      af[i]  = ldfrag(u.s.As + (wy * 64 + i * 16 + ln) * 32 + qd * 8);
      bfr[i] = ldfrag(u.s.Bs + (wx * 64 + i * 16 + ln) * 32 + qd * 8);
    }
#pragma unroll
    for (int i = 0; i < 4; ++i)
#pragma unroll
      for (int j = 0; j < 4; ++j)
        acc[i][j] = __builtin_amdgcn_mfma_f32_16x16x32_bf16(af[i], bfr[j], acc[i][j], 0, 0, 0);
    __syncthreads();
  }

  float qnj[4], q2j[4];
#pragma unroll
  for (int j = 0; j < 4; ++j) {
    int m = wx * 64 + j * 16 + ln;
    qnj[j] = qnegs[m];
    q2j[j] = q2s[m];
  }
#pragma unroll
  for (int i = 0; i < 4; ++i)
#pragma unroll
    for (int r = 0; r < 4; ++r) {
      int ll = wy * 64 + i * 16 + qd * 4 + r;
      float cv = c1s[ll];
#pragma unroll
      for (int j = 0; j < 4; ++j) acc[i][j][r] += cv + q2j[j];
    }

  // row max
#pragma unroll
  for (int i = 0; i < 4; ++i)
#pragma unroll
    for (int r = 0; r < 4; ++r) {
      float v = -INFINITY;
#pragma unroll
      for (int j = 0; j < 4; ++j) v = fmaxf(v, acc[i][j][r] + qnj[j]);
      v = fmaxf(v, __shfl_xor(v, 1));
      v = fmaxf(v, __shfl_xor(v, 2));
      v = fmaxf(v, __shfl_xor(v, 4));
      v = fmaxf(v, __shfl_xor(v, 8));
      if (ln == 0) rowred[wy * 64 + i * 16 + qd * 4 + r][wx] = v;
    }
  __syncthreads();
  if (t < 128) {
    float v = fmaxf(fmaxf(rowred[t][0], rowred[t][1]), fmaxf(rowred[t][2], rowred[t][3]));
    rmaxs[t] = v;
    rcs[t] = v + cnegs[t];
  }
  __syncthreads();
  if (t < 64) {
    float v = fmaxf(rcs[t], rcs[t + 64]);
    v = fmaxf(v, __shfl_xor(v, 1));
    v = fmaxf(v, __shfl_xor(v, 2));
    v = fmaxf(v, __shfl_xor(v, 4));
    v = fmaxf(v, __shfl_xor(v, 8));
    v = fmaxf(v, __shfl_xor(v, 16));
    v = fmaxf(v, __shfl_xor(v, 32));
    if (t == 0) chunkmax_s = v;
  }
  __syncthreads();
  if (t < 128) rcs[t] = __expf(rcs[t] - chunkmax_s);  // rowfac
  __syncthreads();

  // e1, row sums, column partial sums
  float cs[4] = {0.f, 0.f, 0.f, 0.f};
#pragma unroll
  for (int i = 0; i < 4; ++i)
#pragma unroll
    for (int r = 0; r < 4; ++r) {
      int ll = wy * 64 + i * 16 + qd * 4 + r;
      float rmx = rmaxs[ll], rf = rcs[ll];
      float rs = 0.f;
#pragma unroll
      for (int j = 0; j < 4; ++j) {
        float e = __expf(acc[i][j][r] + qnj[j] - rmx);
        acc[i][j][r] = e;
        rs += e;
        cs[j] += e * rf;
      }
      rs += __shfl_xor(rs, 1);
      rs += __shfl_xor(rs, 2);
      rs += __shfl_xor(rs, 4);
      rs += __shfl_xor(rs, 8);
      if (ln == 0) rowsum[ll][wx] = rs;
    }
#pragma unroll
  for (int j = 0; j < 4; ++j) {
    float v = cs[j];
    v += __shfl_xor(v, 16);
    v += __shfl_xor(v, 32);
    if (qd == 0) colred[wx * 64 + j * 16 + ln][wy] = v;
  }
  __syncthreads();
  if (t < 128)
    rscale_g[b * NLC + l0 + t] =
        1.f / (rowsum[t][0] + rowsum[t][1] + rowsum[t][2] + rowsum[t][3]);
  if (t >= 256 && t < 512) {
    int m = t - 256;
    psum_part[(b * 8 + chunk) * NLQ + m] = colred[m][0] + colred[m][1];
  }
  if (t == 0) chunkmax_g[b * 8 + chunk] = chunkmax_s;

  // ---- e1 bounce + coalesced store ----
#pragma unroll
  for (int i = 0; i < 4; ++i)
#pragma unroll
    for (int r = 0; r < 4; ++r) {
      int ll = wy * 64 + i * 16 + qd * 4 + r;
#pragma unroll
      for (int j = 0; j < 4; ++j)
        u.bounce[ll * 264 + wx * 64 + j * 16 + ln] = f2bf(acc[i][j][r]);
    }
  __syncthreads();
  {
    ushort* Eb = e1g + (size_t)b * NLC * NLQ;
#pragma unroll
    for (int p = 0; p < 4; ++p) {
      int idx4 = p * 512 + t;
      int r = idx4 >> 4, c = (idx4 & 15) * 16;
      *(int4*)(Eb + (size_t)(l0 + r) * NLQ + c) = *(const int4*)(u.bounce + r * 264 + c);
      *(int4*)(Eb + (size_t)(l0 + r) * NLQ + c + 8) = *(const int4*)(u.bounce + r * 264 + c + 8);
    }
  }
  __syncthreads();

  // ---- h bounce (transposed, chunk-factor folded) + coalesced store ----
#pragma unroll
  for (int i = 0; i < 4; ++i)
#pragma unroll
    for (int r = 0; r < 4; ++r) {
      int ll = wy * 64 + i * 16 + qd * 4 + r;
      float rf = rcs[ll];
#pragma unroll
      for (int j = 0; j < 4; ++j)
        u.hb[(wx * 64 + j * 16 + ln) * 132 + ll] = f2bf(acc[i][j][r] * rf);
    }
  __syncthreads();
  {
    ushort* Hb = hg + (size_t)b * NLQ * NLC;
#pragma unroll
    for (int p = 0; p < 8; ++p) {
      int idx = p * 512 + t;
      int m = idx >> 4, sg = (idx & 15) * 8;
      *(int4*)(Hb + (size_t)m * NLC + l0 + sg) = *(const int4*)(u.hb + m * 132 + sg);
    }
  }
}

// -------------------------------------------------------------------------
__global__ __launch_bounds__(256) void stat_combine(
    const float* __restrict__ psum_part, const float* __restrict__ chunkmax_g,
    float* __restrict__ cinv) {
  __shared__ float cm[8];
  int b = blockIdx.x, t = threadIdx.x;
  if (t < 8) cm[t] = chunkmax_g[b * 8 + t];
  __syncthreads();
  float K = cm[0];
#pragma unroll
  for (int c = 1; c < 8; ++c) K = fmaxf(K, cm[c]);
  float s = 0.f;
#pragma unroll
  for (int c = 0; c < 8; ++c)
    s += psum_part[(b * 8 + c) * NLQ + t] * __expf(cm[c] - K);
  cinv[b * NLQ + t] = 1.f / s;
}

// -------------------------------------------------------------------------
// Tpart[b][ks][d][m] = sum_{l in chunk ks} Cn16[d][l] * h[m][l]
// Pure-copy staging, both operands K(l)-contiguous.
__global__ __launch_bounds__(512) void tmat_mfma(
    const ushort* __restrict__ Cn16, const ushort* __restrict__ hg,
    float* __restrict__ Tpart) {
  __shared__ __align__(16) ushort As[128 * 32];
  __shared__ __align__(16) ushort Bs[256 * 32];
  int b = blockIdx.y, ks = blockIdx.x, lbase = ks * 128;
  int t = threadIdx.x, lane = t & 63, wid = t >> 6;
  int wy = wid >> 2, wx = wid & 3, ln = lane & 15, qd = lane >> 4;
  const ushort* Cb = Cn16 + (size_t)b * ND * NLC;
  const ushort* Hb = hg + (size_t)b * NLQ * NLC;
  f32x4 acc[4][4];
#pragma unroll
  for (int i = 0; i < 4; ++i)
#pragma unroll
    for (int j = 0; j < 4; ++j) acc[i][j] = (f32x4){0.f, 0.f, 0.f, 0.f};

  for (int c0 = 0; c0 < 128; c0 += 32) {
    {
      int r = t >> 2, cc = (t & 3) * 8;
      *(int4*)(As + r * 32 + cc) = *(const int4*)(Cb + (size_t)r * NLC + lbase + c0 + cc);
    }
#pragma unroll
    for (int p = 0; p < 2; ++p) {
      int e4 = p * 512 + t;
      int r = e4 >> 2, cc = (e4 & 3) * 8;
      *(int4*)(Bs + r * 32 + cc) = *(const int4*)(Hb + (size_t)r * NLC + lbase + c0 + cc);
    }
    __syncthreads();
    bf16x8 af[4], bfr[4];
#pragma unroll
    for (int i = 0; i < 4; ++i) {
      af[i]  = ldfrag(As + (wy * 64 + i * 16 + ln) * 32 + qd * 8);
      bfr[i] = ldfrag(Bs + (wx * 64 + i * 16 + ln) * 32 + qd * 8);
    }
#pragma unroll
    for (int i = 0; i < 4; ++i)
#pragma unroll
      for (int j = 0; j < 4; ++j)
        acc[i][j] = __builtin_amdgcn_mfma_f32_16x16x32_bf16(af[i], bfr[j], acc[i][j], 0, 0, 0);
    __syncthreads();
  }
  float* Tb = Tpart + ((size_t)(b * 8 + ks)) * ND * NLQ;
#pragma unroll
  for (int i = 0; i < 4; ++i)
#pragma unroll
    for (int r = 0; r < 4; ++r) {
      int d = wy * 64 + i * 16 + qd * 4 + r;
#pragma unroll
      for (int j = 0; j < 4; ++j) {
        int m = wx * 64 + j * 16 + ln;
        Tb[(size_t)d * NLQ + m] = acc[i][j][r];
      }
    }
}

// -------------------------------------------------------------------------
// Tt[d][m] = cinv[m] * sum_ks exp(cm[ks]-K) * Tpart[ks][d][m]
__global__ __launch_bounds__(256) void tcombine(
    const float* __restrict__ Tpart, const float* __restrict__ chunkmax_g,
    const float* __restrict__ cinv, ushort* __restrict__ Tt) {
  int gid = blockIdx.x * 256 + threadIdx.x;
  int e = gid * 4;
  int b = e >> 15;
  int r = e & 32767;
  int m = r & 255;
  float cm[8];
#pragma unroll
  for (int c = 0; c < 8; ++c) cm[c] = chunkmax_g[b * 8 + c];
  float K = cm[0];
#pragma unroll
  for (int c = 1; c < 8; ++c) K = fmaxf(K, cm[c]);
  float4 s = {0.f, 0.f, 0.f, 0.f};
#pragma unroll
  for (int ks = 0; ks < 8; ++ks) {
    float f = __expf(cm[ks] - K);
    float4 v = *(const float4*)(Tpart + ((size_t)(b * 8 + ks)) * ND * NLQ + r);
    s.x += f * v.x; s.y += f * v.y; s.z += f * v.z; s.w += f * v.w;
  }
  float4 ci = *(const float4*)(cinv + b * NLQ + m);
  ushort4 o;
  o.x = f2bf(s.x * ci.x); o.y = f2bf(s.y * ci.y);
  o.z = f2bf(s.z * ci.z); o.w = f2bf(s.w * ci.w);
  *(ushort4*)(Tt + (size_t)b * ND * NLQ + r) = o;
}

// -------------------------------------------------------------------------
// A[d][l] = sum_m Qn16[d][m]*e1[l][m]; Bv[d][l] = sum_m Tt[d][m]*e1[l][m];
// scale by rscale[l]; write all 4 output channel groups.
__global__ __launch_bounds__(256, 2) void outk(
    const float* __restrict__ C, const ushort* __restrict__ Qn16,
    const ushort* __restrict__ Tt, const ushort* __restrict__ e1g,
    const float* __restrict__ rscale, float* __restrict__ out) {
  __shared__ __align__(16) ushort As1[128 * 32];
  __shared__ __align__(16) ushort As2[128 * 32];
  __shared__ __align__(16) ushort Bs[128 * 32];
  int b = blockIdx.y;
  int l0 = blockIdx.x * 128;
  const ushort* Qb = Qn16 + (size_t)b * ND * NLQ;
  const ushort* Tb = Tt + (size_t)b * ND * NLQ;
  const ushort* Eb = e1g + (size_t)b * NLC * NLQ;
  int t = threadIdx.x, lane = t & 63, wid = t >> 6, wy = wid >> 1, wx = wid & 1;
  int ln = lane & 15, qd = lane >> 4;
  f32x4 acc1[4][4], acc2[4][4];
#pragma unroll
  for (int i = 0; i < 4; ++i)
#pragma unroll
    for (int j = 0; j < 4; ++j) {
      acc1[i][j] = (f32x4){0.f, 0.f, 0.f, 0.f};
      acc2[i][j] = (f32x4){0.f, 0.f, 0.f, 0.f};
    }

  for (int m0 = 0; m0 < NLQ; m0 += 32) {
#pragma unroll
    for (int p = 0; p < 2; ++p) {
      int e = t * 8 + p * 2048;
      int r = e >> 5, cc = e & 31;
      *(int4*)(As1 + e) = *(const int4*)(Qb + (size_t)r * NLQ + m0 + cc);
      *(int4*)(As2 + e) = *(const int4*)(Tb + (size_t)r * NLQ + m0 + cc);
      *(int4*)(Bs + e)  = *(const int4*)(Eb + (size_t)(l0 + r) * NLQ + m0 + cc);
    }
    __syncthreads();
    bf16x8 a1[4], a2[4], bfr[4];
#pragma unroll
    for (int i = 0; i < 4; ++i) {
      a1[i] = ldfrag(As1 + (wy * 64 + i * 16 + ln) * 32 + qd * 8);
      a2[i] = ldfrag(As2 + (wy * 64 + i * 16 + ln) * 32 + qd * 8);
      bfr[i] = ldfrag(Bs + (wx * 64 + i * 16 + ln) * 32 + qd * 8);
    }
#pragma unroll
    for (int i = 0; i < 4; ++i)
#pragma unroll
      for (int j = 0; j < 4; ++j) {
        acc1[i][j] = __builtin_amdgcn_mfma_f32_16x16x32_bf16(a1[i], bfr[j], acc1[i][j], 0, 0, 0);
        acc2[i][j] = __builtin_amdgcn_mfma_f32_16x16x32_bf16(a2[i], bfr[j], acc2[i][j], 0, 0, 0);
      }
    __syncthreads();
  }

  const float* Cb = C + (size_t)b * ND * NLC;
  float* outb = out + (size_t)b * 4 * ND * NLC;
#pragma unroll
  for (int j = 0; j < 4; ++j) {
    int l = l0 + wx * 64 + j * 16 + ln;
    float rs = rscale[b * NLC + l];
#pragma unroll
    for (int i = 0; i < 4; ++i)
#pragma unroll
      for (int r = 0; r < 4; ++r) {
        int d = wy * 64 + i * 16 + qd * 4 + r;
        float a = acc1[i][j][r] * rs;
        float bv = acc2[i][j][r] * rs;
        float c = Cb[(size_t)d * NLC + l];
        outb[(size_t)d * NLC + l] = c;
        outb[(size_t)(128 + d) * NLC + l] = a;
        outb[(size_t)(256 + d) * NLC + l] = c * a;
        outb[(size_t)(384 + d) * NLC + l] = c * bv;
      }
  }
}

// -------------------------------------------------------------------------
extern "C" void kernel_launch(void* const* d_in, const int* in_sizes, int n_in,
                              void* d_out, int out_size, void* d_ws, size_t ws_size,
                              hipStream_t stream) {
  const float* C     = (const float*)d_in[0];
  const float* Q     = (const float*)d_in[1];
  const float* cmask = (const float*)d_in[2];
  const float* qmask = (const float*)d_in[3];
  const float* w     = (const float*)d_in[4];
  float* out = (float*)d_out;

  char* p = (char*)d_ws;
  auto alloc = [&](size_t bytes) { char* r = p; p += (bytes + 255) & ~(size_t)255; return r; };
  ushort* e1g   = (ushort*)alloc((size_t)NB * NLC * NLQ * 2);
  ushort* hg    = (ushort*)alloc((size_t)NB * NLQ * NLC * 2);
  ushort* Ctw3  = (ushort*)alloc((size_t)NB * NLC * ND * 2);
  ushort* Qt16  = (ushort*)alloc((size_t)NB * NLQ * ND * 2);
  ushort* Cn16  = (ushort*)alloc((size_t)NB * ND * NLC * 2);
  ushort* Qn16  = (ushort*)alloc((size_t)NB * ND * NLQ * 2);
  float*  Tpart = (float*)alloc((size_t)NB * 8 * ND * NLQ * 4);
  ushort* Tt    = (ushort*)alloc((size_t)NB * ND * NLQ * 2);
  float*  c1    = (float*)alloc((size_t)NB * NLC * 4);
  float*  q2    = (float*)alloc((size_t)NB * NLQ * 4);
  float*  rscale= (float*)alloc((size_t)NB * NLC * 4);
  float*  cinv  = (float*)alloc((size_t)NB * NLQ * 4);
  float*  psum  = (float*)alloc((size_t)NB * 8 * NLQ * 4);
  float*  chmax = (float*)alloc((size_t)NB * 8 * 4);

  convert_bias<<<dim3(20, NB), 256, 0, stream>>>(C, Q, w, Ctw3, Qt16, Cn16, Qn16, c1, q2);
  score_stats<<<dim3(NLC / 128, NB), 512, 0, stream>>>(
      Ctw3, Qt16, c1, q2, cmask, qmask, e1g, hg, rscale, psum, chmax);
  stat_combine<<<NB, 256, 0, stream>>>(psum, chmax, cinv);
  tmat_mfma<<<dim3(8, NB), 512, 0, stream>>>(Cn16, hg, Tpart);
  tcombine<<<(NB * ND * NLQ / 4) / 256, 256, 0, stream>>>(Tpart, chmax, cinv, Tt);
  outk<<<dim3(NLC / 128, NB), 256, 0, stream>>>(C, Qn16, Tt, e1g, rscale, out);
}